// Round 6
// baseline (770.033 us; speedup 1.0000x reference)
//
#include <hip/hip_runtime.h>
#include <math.h>

#define NB 32
#define NM 8
#define HOBJ 1024
// row-kernel exchange: per-group [8][EXROW] f2, region stride EXREG f2
// (EXREG=152 f2 = 304 f32 == 16 mod 32 -> adjacent groups staggered 16 banks)
#define EXROW 18
#define EXREG 152
// col-kernel exchange stride in floats (== 2 mod 32, r1-proven)
#define CSTR 290

// zero-instruction compiler fence: wave-local LDS exchange relies on same-wave
// DS program order (HW-guaranteed); this stops compiler reordering the
// float4-punned stores vs float2 loads.
#define CFENCE() __asm__ volatile("" ::: "memory")

__device__ __forceinline__ float2 cmul(float2 a, float2 b) {
    return make_float2(fmaf(a.x, b.x, -a.y * b.y), fmaf(a.x, b.y, a.y * b.x));
}

__constant__ float COS16[10] = {1.f, 0.9238795325f, 0.7071067812f, 0.3826834324f, 0.f,
                                -0.3826834324f, -0.7071067812f, -0.9238795325f, -1.f, -0.9238795325f};
__constant__ float SIN16[10] = {0.f, 0.3826834324f, 0.7071067812f, 0.9238795325f, 1.f,
                                0.9238795325f, 0.7071067812f, 0.3826834324f, 0.f, -0.3826834324f};

template <int S>
__device__ __forceinline__ void dft4(float2 a, float2 b, float2 c, float2 d,
                                     float2* o0, float2* o1, float2* o2, float2* o3) {
    float2 apc = make_float2(a.x + c.x, a.y + c.y);
    float2 amc = make_float2(a.x - c.x, a.y - c.y);
    float2 bpd = make_float2(b.x + d.x, b.y + d.y);
    float2 bmd = make_float2(b.x - d.x, b.y - d.y);
    float2 ib = (S < 0) ? make_float2(bmd.y, -bmd.x) : make_float2(-bmd.y, bmd.x);
    *o0 = make_float2(apc.x + bpd.x, apc.y + bpd.y);
    *o1 = make_float2(amc.x + ib.x, amc.y + ib.y);
    *o2 = make_float2(apc.x - bpd.x, apc.y - bpd.y);
    *o3 = make_float2(amc.x - ib.x, amc.y - ib.y);
}

template <int S>
__device__ __forceinline__ void fft16(float2 v[16]) {
    float2 t[16];
#pragma unroll
    for (int b = 0; b < 4; ++b)
        dft4<S>(v[b], v[4 + b], v[8 + b], v[12 + b],
                &t[4 * b + 0], &t[4 * b + 1], &t[4 * b + 2], &t[4 * b + 3]);
#pragma unroll
    for (int b = 1; b < 4; ++b)
#pragma unroll
        for (int c = 1; c < 4; ++c) {
            int j = b * c;  // 1..9
            float2 w = make_float2(COS16[j], (S < 0) ? -SIN16[j] : SIN16[j]);
            t[4 * b + c] = cmul(t[4 * b + c], w);
        }
#pragma unroll
    for (int c = 0; c < 4; ++c)
        dft4<S>(t[c], t[4 + c], t[8 + c], t[12 + c],
                &v[c + 0], &v[c + 4], &v[c + 8], &v[c + 12]);
}

// ---- barrier-free 256-pt FFT for ROW kernels (16-lane quarter-wave groups) ----
// in v[n1]=x[16n1+t]; out v[k2]=X[16k2+t]. ex = per-group [8][EXROW] f2 region.
template <int S>
__device__ __forceinline__ void fft256w(float2 v[16], int t, float2* ex) {
    fft16<S>(v);
#pragma unroll
    for (int k = 1; k < 16; ++k) {
        float sn, cs;
        __sincosf((float)S * 0.024543692606f * (float)(t * k), &sn, &cs);  // 2pi/256
        v[k] = cmul(v[k], make_float2(cs, sn));
    }
    CFENCE();
    if (t < 8) {
        float2* row = ex + t * EXROW;
#pragma unroll
        for (int c = 0; c < 8; ++c) {
            float4 f;
            f.x = v[2 * c].x; f.y = v[2 * c].y; f.z = v[2 * c + 1].x; f.w = v[2 * c + 1].y;
            *(float4*)(row + 2 * c) = f;
        }
    }
    CFENCE();
    float2 w0[8];
#pragma unroll
    for (int j = 0; j < 8; ++j) w0[j] = ex[j * EXROW + t];
    CFENCE();
    if (t >= 8) {
        float2* row = ex + (t - 8) * EXROW;
#pragma unroll
        for (int c = 0; c < 8; ++c) {
            float4 f;
            f.x = v[2 * c].x; f.y = v[2 * c].y; f.z = v[2 * c + 1].x; f.w = v[2 * c + 1].y;
            *(float4*)(row + 2 * c) = f;
        }
    }
    CFENCE();
#pragma unroll
    for (int j = 0; j < 8; ++j) v[8 + j] = ex[j * EXROW + t];
    CFENCE();
#pragma unroll
    for (int j = 0; j < 8; ++j) v[j] = w0[j];
    fft16<S>(v);
}

// ---- barrier version for COL kernels (groups span waves; r1-proven) ----
template <int S>
__device__ __forceinline__ void fft256b(float2 v[16], int t, float* ldsRe, float* ldsIm) {
    fft16<S>(v);
#pragma unroll
    for (int k = 1; k < 16; ++k) {
        float sn, cs;
        __sincosf((float)S * 0.024543692606f * (float)(t * k), &sn, &cs);
        v[k] = cmul(v[k], make_float2(cs, sn));
    }
    __syncthreads();
#pragma unroll
    for (int k = 0; k < 16; ++k) {
        ldsRe[k * 17 + t] = v[k].x;
        ldsIm[k * 17 + t] = v[k].y;
    }
    __syncthreads();
#pragma unroll
    for (int j = 0; j < 16; ++j) {
        v[j].x = ldsRe[t * 17 + j];
        v[j].y = ldsIm[t * 17 + j];
    }
    fft16<S>(v);
}

// ---------- P1 (row, barrier-free): build 39 unique probe images + row FFT ----------
// i in [0,32): per-b OPR mode-0 combo; i in [32,39): shared mode m=i-31.
__global__ void __launch_bounds__(256, 8)
k_p1(const float* __restrict__ probe, const float* __restrict__ opr_w,
     const int* __restrict__ indices, float2* __restrict__ S) {
    __shared__ __align__(16) float2 lds[16 * EXREG];
    int tt = threadIdx.x;
    int t = tt & 15, g = tt >> 4;
    int rowg = blockIdx.x, i = blockIdx.y;
    int y = rowg * 16 + g;
    float2* ex = lds + g * EXREG;
    float2 v[16];
    if (i < 32) {
        int idx = indices[i];
        float w0 = opr_w[idx * 4 + 0], w1 = opr_w[idx * 4 + 1];
        float w2 = opr_w[idx * 4 + 2], w3 = opr_w[idx * 4 + 3];
        const float2* p = (const float2*)probe;
        size_t rb = (size_t)y * 256;
#pragma unroll
        for (int j = 0; j < 16; ++j) {
            size_t o = rb + 16 * j + t;
            float2 p0 = p[o];
            float2 p1 = p[(size_t)(1 * NM) * 65536 + o];
            float2 p2 = p[(size_t)(2 * NM) * 65536 + o];
            float2 p3 = p[(size_t)(3 * NM) * 65536 + o];
            v[j] = make_float2(w0 * p0.x + w1 * p1.x + w2 * p2.x + w3 * p3.x,
                               w0 * p0.y + w1 * p1.y + w2 * p2.y + w3 * p3.y);
        }
    } else {
        const float2* p = (const float2*)probe + (size_t)(i - 31) * 65536 + (size_t)y * 256;
#pragma unroll
        for (int j = 0; j < 16; ++j) v[j] = p[16 * j + t];
    }
    fft256w<-1>(v, t, ex);
    float2* ob = S + (size_t)i * 65536 + (size_t)y * 256;
#pragma unroll
    for (int k2 = 0; k2 < 16; ++k2) ob[k2 * 16 + t] = v[k2];
}

// ---------- P2 (col): read S, yF * full 2D shift phase * yI -> psi ----------
__global__ void __launch_bounds__(256, 4)
k_p2(const float* __restrict__ positions, const int* __restrict__ indices,
     const float2* __restrict__ S, float2* __restrict__ buf, int b0) {
    __shared__ float sRe[16 * CSTR], sIm[16 * CSTR];
    int tt = threadIdx.x;
    int c = tt & 15, t = tt >> 4;
    int colg = blockIdx.x, m = blockIdx.y, bl = blockIdx.z;
    int b = b0 + bl;
    int x = colg * 16 + c;  // = kx
    int idx = indices[b];
    float py = positions[idx * 2 + 0], px = positions[idx * 2 + 1];
    float fr0 = py - rintf(py), fr1 = px - rintf(px);
    float fxv = (float)((x < 128) ? x : x - 256) * (1.0f / 256.0f);
    const float2* src = S + (size_t)((m == 0) ? b : 31 + m) * 65536;
    float2* img = buf + (size_t)(bl * NM + m) * 65536;
    float2 v[16];
#pragma unroll
    for (int n1 = 0; n1 < 16; ++n1) v[n1] = src[(size_t)(n1 * 16 + t) * 256 + x];
    fft256b<-1>(v, t, &sRe[c * CSTR], &sIm[c * CSTR]);
#pragma unroll
    for (int k2 = 0; k2 < 16; ++k2) {
        int ky = t + 16 * k2;
        float fyv = (float)((ky < 128) ? ky : ky - 256) * (1.0f / 256.0f);
        float ang = -6.2831853071795865f * (fr0 * fyv + fr1 * fxv);
        float sn, cs;
        __sincosf(ang, &sn, &cs);
        v[k2] = cmul(v[k2], make_float2(cs, sn));
    }
    fft256b<1>(v, t, &sRe[c * CSTR], &sIm[c * CSTR]);
#pragma unroll
    for (int j = 0; j < 16; ++j) {
        float2 r = make_float2(v[j].x * (1.0f / 256.0f), v[j].y * (1.0f / 256.0f));
        img[(size_t)(j * 16 + t) * 256 + x] = r;
    }
}

// ---------- P3 (row, barrier-free, in-place): xI * object slice * xF ----------
__global__ void __launch_bounds__(256, 8)
k_p3(const float* __restrict__ object, const float* __restrict__ positions,
     const int* __restrict__ indices, float2* __restrict__ buf, int b0, int s) {
    __shared__ __align__(16) float2 lds[16 * EXREG];
    int tt = threadIdx.x;
    int t = tt & 15, g = tt >> 4;
    int rowg = blockIdx.x, m = blockIdx.y, bl = blockIdx.z;
    int b = b0 + bl;
    int y = rowg * 16 + g;
    int idx = indices[b];
    int r0 = (int)rintf(positions[idx * 2 + 0]);
    int r1 = (int)rintf(positions[idx * 2 + 1]);
    float2* ex = lds + g * EXREG;
    float2* img = buf + (size_t)(bl * NM + m) * 65536 + (size_t)y * 256;
    float2 v[16];
#pragma unroll
    for (int n1 = 0; n1 < 16; ++n1) v[n1] = img[n1 * 16 + t];
    fft256w<1>(v, t, ex);
    const float2* obj = (const float2*)object + (size_t)s * HOBJ * HOBJ + (size_t)(r0 + y) * HOBJ + r1 + t;
#pragma unroll
    for (int j = 0; j < 16; ++j) {
        float2 pz = obj[16 * j];
        float2 ps = make_float2(v[j].x * (1.0f / 256.0f), v[j].y * (1.0f / 256.0f));
        v[j] = cmul(ps, pz);
    }
    fft256w<-1>(v, t, ex);
#pragma unroll
    for (int k2 = 0; k2 < 16; ++k2) img[k2 * 16 + t] = v[k2];
}

// ---------- P4 (col, in-place): yF * TF * yI ----------
__global__ void __launch_bounds__(256, 4)
k_p4(const float2* __restrict__ tf, float2* __restrict__ buf) {
    __shared__ float sRe[16 * CSTR], sIm[16 * CSTR];
    int tt = threadIdx.x;
    int c = tt & 15, t = tt >> 4;
    int colg = blockIdx.x, m = blockIdx.y, bl = blockIdx.z;
    int x = colg * 16 + c;
    float2* img = buf + (size_t)(bl * NM + m) * 65536;
    float2 v[16];
#pragma unroll
    for (int n1 = 0; n1 < 16; ++n1) v[n1] = img[(size_t)(n1 * 16 + t) * 256 + x];
    fft256b<-1>(v, t, &sRe[c * CSTR], &sIm[c * CSTR]);
#pragma unroll
    for (int k2 = 0; k2 < 16; ++k2) {
        int ky = t + 16 * k2;
        v[k2] = cmul(v[k2], tf[ky * 256 + x]);
    }
    fft256b<1>(v, t, &sRe[c * CSTR], &sIm[c * CSTR]);
#pragma unroll
    for (int j = 0; j < 16; ++j) {
        float2 r = make_float2(v[j].x * (1.0f / 256.0f), v[j].y * (1.0f / 256.0f));
        img[(size_t)(j * 16 + t) * 256 + x] = r;
    }
}

// ---------- P10 (col): yF, |.|^2, sum modes, shifted store ----------
__global__ void __launch_bounds__(256, 4)
k_p10(const float2* __restrict__ buf, float* __restrict__ out, int b0) {
    __shared__ float sRe[16 * CSTR], sIm[16 * CSTR];
    int tt = threadIdx.x;
    int c = tt & 15, t = tt >> 4;
    int colg = blockIdx.x, bl = blockIdx.z;
    int x = colg * 16 + c;  // = kx
    float acc[16];
#pragma unroll
    for (int j = 0; j < 16; ++j) acc[j] = 0.f;
    for (int m = 0; m < NM; ++m) {
        const float2* img = buf + (size_t)(bl * NM + m) * 65536;
        float2 v[16];
#pragma unroll
        for (int n1 = 0; n1 < 16; ++n1) v[n1] = img[(size_t)(n1 * 16 + t) * 256 + x];
        fft256b<-1>(v, t, &sRe[c * CSTR], &sIm[c * CSTR]);
#pragma unroll
        for (int k2 = 0; k2 < 16; ++k2)
            acc[k2] = fmaf(v[k2].x, v[k2].x, fmaf(v[k2].y, v[k2].y, acc[k2]));
    }
    float* ob = out + (size_t)(b0 + bl) * 65536;
    int xs = (x + 128) & 255;
#pragma unroll
    for (int k2 = 0; k2 < 16; ++k2) {
        int ys = ((t + 16 * k2) + 128) & 255;
        ob[ys * 256 + xs] = acc[k2] * (1.0f / 65536.0f);  // ortho norm squared
    }
}

// ---------- TF table [ky][kx] (double precision: phase ~1e5 rad) ----------
__global__ void k_tf(float2* __restrict__ tf) {
    int i = blockIdx.x * 256 + threadIdx.x;
    int ky = i >> 8, kx = i & 255;
    double fy = (double)((ky < 128) ? ky : ky - 256) / (256.0 * 1.0e-8);
    double fx = (double)((kx < 128) ? kx : kx - 256) / (256.0 * 1.0e-8);
    double ly = 1.24e-10 * fy, lx = 1.24e-10 * fx;
    double arg = 1.0 - lx * lx - ly * ly;
    float2 r = make_float2(0.f, 0.f);
    if (arg > 0.0) {
        double kz = (2.0 * M_PI / 1.24e-10) * sqrt(arg);
        double ph = 2.0e-6 * kz;
        r = make_float2((float)cos(ph), (float)sin(ph));
    }
    tf[i] = r;
}

extern "C" void kernel_launch(void* const* d_in, const int* in_sizes, int n_in,
                              void* d_out, int out_size, void* d_ws, size_t ws_size,
                              hipStream_t stream) {
    const float* object = (const float*)d_in[0];
    const float* probe = (const float*)d_in[1];
    const float* opr_w = (const float*)d_in[2];
    const float* positions = (const float*)d_in[3];
    const int* indices = (const int*)d_in[4];
    float* out = (float*)d_out;

    float2* tf = (float2*)d_ws;                                // 512 KB
    float2* S = (float2*)((char*)d_ws + (1 << 20));            // 39 probe-FFT images, 20.4 MB
    char* after_S = (char*)d_ws + (1 << 20) + 39ll * 65536 * sizeof(float2);
    float2* buf = (float2*)after_S;                            // psi, in-place passes
    size_t avail = (size_t)((char*)d_ws + ws_size - after_S);
    long long perb = (long long)NM * 65536 * sizeof(float2);   // 4 MB per batch entry
    int Bc = (int)(avail / perb);
    if (Bc > NB) Bc = NB;
    if (Bc < 1) Bc = 1;

    k_tf<<<256, 256, 0, stream>>>(tf);
    k_p1<<<dim3(16, 39), 256, 0, stream>>>(probe, opr_w, indices, S);

    for (int b0 = 0; b0 < NB; b0 += Bc) {
        int bc = (NB - b0 < Bc) ? (NB - b0) : Bc;
        dim3 grid(16, NM, bc);
        k_p2<<<grid, 256, 0, stream>>>(positions, indices, S, buf, b0);
        for (int s = 0; s < 4; ++s) {
            k_p3<<<grid, 256, 0, stream>>>(object, positions, indices, buf, b0, s);
            if (s < 3) k_p4<<<grid, 256, 0, stream>>>(tf, buf);
        }
        dim3 gridE(16, 1, bc);
        k_p10<<<gridE, 256, 0, stream>>>(buf, out, b0);
    }
}